// Round 30
// baseline (123.278 us; speedup 1.0000x reference)
//
#include <hip/hip_runtime.h>

#define EPSf 1e-5f
#define NPAD 72     // win/f2w ci stride: 16B-aligned b128
#define CSTR 168    // cbuf row stride (corr)

typedef __attribute__((ext_vector_type(8))) short short8;
typedef __attribute__((ext_vector_type(4))) float f32x4;
typedef __attribute__((ext_vector_type(16))) float f32x16;

static __device__ __forceinline__ unsigned short f32_to_bf16(float f) {
    unsigned int u = __float_as_uint(f);
    unsigned int r = (u + 0x7FFFu + ((u >> 16) & 1u)) >> 16;
    return (unsigned short)r;
}
static __device__ __forceinline__ float bf16_to_f32(unsigned short h) {
    return __uint_as_float(((unsigned int)h) << 16);
}

// Pack conv weights into 32x32x16 B-fragment order (r29-validated). grid 2, block 256.
__global__ __launch_bounds__(256) void prep_wfrag(
    const float* __restrict__ wK, const float* __restrict__ wQ,
    unsigned short* __restrict__ fK, unsigned short* __restrict__ fQ)
{
    const float* src = (blockIdx.x == 0) ? wK : wQ;
    unsigned short* dst = (blockIdx.x == 0) ? fK : fQ;
    const int t = threadIdx.x;
#pragma unroll
    for (int it = 0; it < 18; ++it) {
        int idx = t + it * 256;               // 0..4607
        int l = idx & 63, rest = idx >> 6;    // rest 0..71
        int s = rest % 36, nt = rest / 36;
        int tap = s >> 2, cig = s & 3;
        int cout = nt * 32 + (l & 31), khl = l >> 5;
        short8 v;
#pragma unroll
        for (int e = 0; e < 8; ++e) {
            int ci = cig * 16 + khl * 8 + e;
            ((unsigned short*)&v)[e] = f32_to_bf16(src[(size_t)cout * 576 + ci * 9 + tap]);
        }
        *(short8*)&dst[(size_t)idx * 8] = v;
    }
}

// Pack corr's 1x1-conv weights into GEMM2 A-fragment order (r27-validated).
__global__ __launch_bounds__(256) void prep_w2frag(
    const float* __restrict__ qw, unsigned short* __restrict__ dst)
{
    const int t = threadIdx.x;
    const int wv = t >> 6, l = t & 63;
    const int n = l & 15, kg = l >> 4;
    const int cout = wv * 16 + n;
#pragma unroll
    for (int s = 0; s < 5; ++s) {
        short8 v;
#pragma unroll
        for (int e = 0; e < 8; ++e) {
            int k = s * 32 + kg * 8 + e;
            float w = 0.f;
            if (k < 81)                  w = qw[cout * 145 + k];
            else if (k >= 88 && k < 152) w = qw[cout * 145 + k - 7];
            ((unsigned short*)&v)[e] = f32_to_bf16(w);
        }
        *(short8*)&dst[((wv * 5 + s) * 64 + l) * 8] = v;
    }
}

// Both 3x3 convs, ONE dispatch, 32x32x16 core + XCD swizzle (r29-validated).
// NEW (T14): half-1 staging split into {issue loads -> regs} BEFORE phase-0
// MFMAs and {convert + ds_write} AFTER them (write target ci>=32 is disjoint
// from phase-0 reads ci<32 -> race-free; barrier before phase 1).
__global__ __launch_bounds__(256) void conv3x3_mfma_P(
    const float* __restrict__ fm1, const float* __restrict__ fm2,
    const unsigned short* __restrict__ wfK, const unsigned short* __restrict__ wfQ,
    const float* __restrict__ bK, const float* __restrict__ gK,
    const float* __restrict__ beK, const float* __restrict__ mK, const float* __restrict__ vK,
    const float* __restrict__ bQ, const float* __restrict__ gQ,
    const float* __restrict__ beQ, const float* __restrict__ mQ, const float* __restrict__ vQ,
    unsigned short* __restrict__ f1o, unsigned short* __restrict__ f2o)
{
    __shared__ unsigned short win[10 * 18 * NPAD];
    const int t  = threadIdx.x;
    // ---- XCD swizzle: nwg=2304=8*288, one (which,b) slice per XCD ----
    const int id  = blockIdx.x + 12 * (blockIdx.y + 24 * blockIdx.z);
    const int id2 = (id & 7) * 288 + (id >> 3);
    const int x0 = (id2 % 12) << 4;
    const int y0 = ((id2 / 12) % 24) << 3;
    const int zz = id2 / 288;
    const int b  = zz & 3, which = zz >> 2;

    const float* in = which ? fm2 : fm1;
    const unsigned short* wfrag = which ? wfQ : wfK;
    const float* bias = which ? bQ : bK;
    const float* bn_g = which ? gQ : gK;
    const float* bn_be = which ? beQ : beK;
    const float* bn_m = which ? mQ : mK;
    const float* bn_v = which ? vQ : vK;
    unsigned short* out = which ? f2o : f1o;
    const float* inb = in + (size_t)b * 64 * 36864;

    if (x0 == 0) {
        for (int i = t; i < 640; i += 256) {
            int ci = i & 63, row = i >> 6;
            win[(row * 18 + 0) * NPAD + ci] = 0;
        }
    } else if (x0 == 176) {
        for (int i = t; i < 640; i += 256) {
            int ci = i & 63, row = i >> 6;
            win[(row * 18 + 17) * NPAD + ci] = 0;
        }
    }

    const int gxs = (x0 == 0) ? 0 : ((x0 == 176) ? 168 : x0 - 4);
    const int wv = t >> 6, l = t & 63;
    const int nt = wv & 1, mhalf = wv >> 1;
    const int c31 = l & 31, khl = l >> 5;
    const int cout = nt * 32 + c31;
    const unsigned short* wf = wfrag + (size_t)nt * 36 * 512 + l * 8;

    const float inv = bn_g[cout] / sqrtf(bn_v[cout] + EPSf);
    const float sh  = (bias[cout] - bn_m[cout]) * inv + bn_be[cout];

    f32x16 acc0, acc1;
#pragma unroll
    for (int i = 0; i < 16; ++i) { acc0[i] = 0.f; acc1[i] = 0.f; }

    const int px0 = (mhalf * 2 + 0) * 32 + c31;
    const int px1 = (mhalf * 2 + 1) * 32 + c31;
    const int py0 = px0 >> 4, pxx0 = px0 & 15;
    const int py1 = px1 >> 4, pxx1 = px1 & 15;

    // ---- stage half 0: ci[0,32) (load+convert+write) ----
#pragma unroll
    for (int it = 0; it < 8; ++it) {
        int q = t + (it << 8);
        if (q < 1920) {
            int p = q / 6, j = q - p * 6;
            int ci = p & 31, row = p >> 5;
            int gy = y0 - 1 + row;
            bool rowok = (gy >= 0 && gy < 192);
            int gya = rowok ? gy : (gy < 0 ? 0 : 191);
            int gxa = gxs + j * 4;
            f32x4 v = *(const f32x4*)(inb + (size_t)ci * 36864 + gya * 192 + gxa);
#pragma unroll
            for (int e = 0; e < 4; ++e) {
                int col = gxa + e - (x0 - 1);
                if (col >= 0 && col < 18)
                    win[(row * 18 + col) * NPAD + ci] = f32_to_bf16(rowok ? v[e] : 0.f);
            }
        }
    }
    __syncthreads();

    // ---- T14: ISSUE half-1 loads into registers (no wait, no writes yet) ----
    f32x4 pend[8];
#pragma unroll
    for (int it = 0; it < 8; ++it) {
        int q = t + (it << 8);
        if (q < 1920) {
            int p = q / 6, j = q - p * 6;
            int ci = 32 + (p & 31), row = p >> 5;
            int gy = y0 - 1 + row;
            int gya = (gy >= 0 && gy < 192) ? gy : (gy < 0 ? 0 : 191);
            pend[it] = *(const f32x4*)(inb + (size_t)ci * 36864 + gya * 192 + gxs + j * 4);
        }
    }

    // ---- MFMA phase 0: cig in {0,1} (ci<32) — loads fly under these ----
#pragma unroll
    for (int tap = 0; tap < 9; ++tap) {
#pragma unroll
        for (int cig = 0; cig < 2; ++cig) {
            int s = tap * 4 + cig;
            short8 bfr = *(const short8*)&wf[s * 512];
            int ky = tap / 3, kx = tap - ky * 3;
            int cb = cig * 16 + khl * 8;
            short8 a0 = *(const short8*)&win[((py0 + ky) * 18 + pxx0 + kx) * NPAD + cb];
            short8 a1 = *(const short8*)&win[((py1 + ky) * 18 + pxx1 + kx) * NPAD + cb];
            acc0 = __builtin_amdgcn_mfma_f32_32x32x16_bf16(a0, bfr, acc0, 0, 0, 0);
            acc1 = __builtin_amdgcn_mfma_f32_32x32x16_bf16(a1, bfr, acc1, 0, 0, 0);
        }
    }

    // ---- write half-1 (ci>=32; disjoint from phase-0 reads) ----
#pragma unroll
    for (int it = 0; it < 8; ++it) {
        int q = t + (it << 8);
        if (q < 1920) {
            int p = q / 6, j = q - p * 6;
            int ci = 32 + (p & 31), row = p >> 5;
            int gy = y0 - 1 + row;
            bool rowok = (gy >= 0 && gy < 192);
            int gxa = gxs + j * 4;
            f32x4 v = pend[it];
#pragma unroll
            for (int e = 0; e < 4; ++e) {
                int col = gxa + e - (x0 - 1);
                if (col >= 0 && col < 18)
                    win[(row * 18 + col) * NPAD + ci] = f32_to_bf16(rowok ? v[e] : 0.f);
            }
        }
    }
    __syncthreads();

    // ---- MFMA phase 1: cig in {2,3} (ci>=32) ----
#pragma unroll
    for (int tap = 0; tap < 9; ++tap) {
#pragma unroll
        for (int cig = 2; cig < 4; ++cig) {
            int s = tap * 4 + cig;
            short8 bfr = *(const short8*)&wf[s * 512];
            int ky = tap / 3, kx = tap - ky * 3;
            int cb = cig * 16 + khl * 8;
            short8 a0 = *(const short8*)&win[((py0 + ky) * 18 + pxx0 + kx) * NPAD + cb];
            short8 a1 = *(const short8*)&win[((py1 + ky) * 18 + pxx1 + kx) * NPAD + cb];
            acc0 = __builtin_amdgcn_mfma_f32_32x32x16_bf16(a0, bfr, acc0, 0, 0, 0);
            acc1 = __builtin_amdgcn_mfma_f32_32x32x16_bf16(a1, bfr, acc1, 0, 0, 0);
        }
    }

    // ---- epilogue: D col = l&31 -> cout; row = (r&3)+8*(r>>2)+4*khl -> px ----
    const size_t pbase = (size_t)b * 36864;
#pragma unroll
    for (int mt2 = 0; mt2 < 2; ++mt2) {
#pragma unroll
        for (int r = 0; r < 16; ++r) {
            int rowm = (r & 3) + 8 * (r >> 2) + 4 * khl;
            int px = (mhalf * 2 + mt2) * 32 + rowm;
            int py = px >> 4, pxx = px & 15;
            float v = fmaf(mt2 ? acc1[r] : acc0[r], inv, sh);
            out[(pbase + (size_t)(y0 + py) * 192 + x0 + pxx) * 64 + cout] =
                f32_to_bf16(v > 0.f ? v : 0.f);
        }
    }
}

// Fused corr(R=4) + 1x1 conv — EXACT r28 version (validated, incl. XCD swizzle).
__global__ __launch_bounds__(256) void corr_conv1x1_mfma(
    const unsigned short* __restrict__ f1, const unsigned short* __restrict__ f2,
    const float* __restrict__ qw,
    const unsigned short* __restrict__ w2f,   // may be null
    const float* __restrict__ qb,
    const float* __restrict__ qg, const float* __restrict__ qbe,
    const float* __restrict__ qm, const float* __restrict__ qv,
    float* __restrict__ out)
{
    __shared__ unsigned short smem[20736 + 64 * CSTR];
    unsigned short* f2w  = smem;
    unsigned short* cbuf = smem + 20736;

    const int t  = threadIdx.x;
    const int id  = blockIdx.x + 12 * (blockIdx.y + 48 * blockIdx.z);
    const int id2 = (id & 7) * 288 + (id >> 3);
    const int x0 = (id2 % 12) << 4;
    const int y0 = ((id2 / 12) % 48) << 2;
    const int b  = id2 / 576;

    const int wv = t >> 6, l = t & 63;
    const int n15 = l & 15, kg = l >> 4, hi4 = kg << 2;
    const size_t pbase = (size_t)b * 36864;

#pragma unroll
    for (int i = 0; i < 9; ++i) {
        int q = t + (i << 8);
        int r = q / 192, rem = q - r * 192;
        int u = rem >> 3, j = rem & 7;
        int gy = y0 - 4 + r, gx = x0 - 4 + u;
        short8 v = {0, 0, 0, 0, 0, 0, 0, 0};
        if (gy >= 0 && gy < 192 && gx >= 0 && gx < 192)
            v = *(const short8*)&f2[(pbase + (size_t)gy * 192 + gx) * 64 + j * 8];
        *(short8*)&f2w[(r * 24 + u) * NPAD + j * 8] = v;
    }
#pragma unroll
    for (int i = 0; i < 2; ++i) {
        int q = t + (i << 8);
        int px = q >> 3, j = q & 7;
        int gy = y0 + (px >> 4), gx = x0 + (px & 15);
        short8 v = *(const short8*)&f1[(pbase + (size_t)gy * 192 + gx) * 64 + j * 8];
        *(short8*)&cbuf[px * CSTR + 88 + j * 8] = v;
    }
    if (t < 64) {
#pragma unroll
        for (int d = 81; d < 88; ++d)  cbuf[t * CSTR + d] = 0;
#pragma unroll
        for (int d = 152; d < 168; ++d) cbuf[t * CSTR + d] = 0;
    }

    short8 w2[5];
    if (w2f) {
#pragma unroll
        for (int s = 0; s < 5; ++s)
            w2[s] = *(const short8*)&w2f[((wv * 5 + s) * 64 + l) * 8];
    } else {
        const int cout_a = wv * 16 + n15;
#pragma unroll
        for (int s = 0; s < 5; ++s) {
            short8 v;
#pragma unroll
            for (int e = 0; e < 8; ++e) {
                int k = s * 32 + kg * 8 + e;
                float w = 0.f;
                if (k < 81)                  w = qw[cout_a * 145 + k];
                else if (k >= 88 && k < 152) w = qw[cout_a * 145 + k - 7];
                ((unsigned short*)&v)[e] = f32_to_bf16(w);
            }
            w2[s] = v;
        }
    }
    float inv4[4], sh4[4];
#pragma unroll
    for (int r = 0; r < 4; ++r) {
        int c = wv * 16 + hi4 + r;
        inv4[r] = qg[c] / sqrtf(qv[c] + EPSf);
        sh4[r]  = (qb[c] - qm[c]) * inv4[r] + qbe[c];
    }

    __syncthreads();

    const int ty = wv, tx = n15;
    short8 bfr0 = *(const short8*)&cbuf[(ty * 16 + n15) * CSTR + 88 + kg * 8];
    short8 bfr1 = *(const short8*)&cbuf[(ty * 16 + n15) * CSTR + 120 + kg * 8];
    const int rowb = (ty * 16 + tx) * CSTR;
#pragma unroll
    for (int Mt = 0; Mt < 14; ++Mt) {
        int row = ty * 24 + Mt * 16 + n15;
        short8 a0 = *(const short8*)&f2w[row * NPAD + kg * 8];
        short8 a1 = *(const short8*)&f2w[row * NPAD + 32 + kg * 8];
        f32x4 acc = (f32x4){0.f, 0.f, 0.f, 0.f};
        acc = __builtin_amdgcn_mfma_f32_16x16x32_bf16(a0, bfr0, acc, 0, 0, 0);
        acc = __builtin_amdgcn_mfma_f32_16x16x32_bf16(a1, bfr1, acc, 0, 0, 0);
#pragma unroll
        for (int r = 0; r < 4; ++r) {
            int m  = Mt * 16 + hi4 + r;
            int bb = m / 24;
            int u  = m - bb * 24;
            int a  = u - tx;
            if (m < 216 && a >= 0 && a <= 8)
                cbuf[rowb + a * 9 + bb] = f32_to_bf16(acc[r] * 0.125f);
        }
    }
    __syncthreads();

    f32x4 acc2[4];
#pragma unroll
    for (int Nt = 0; Nt < 4; ++Nt) {
        acc2[Nt] = (f32x4){0.f, 0.f, 0.f, 0.f};
#pragma unroll
        for (int s = 0; s < 5; ++s) {
            short8 bfr = *(const short8*)&cbuf[(Nt * 16 + n15) * CSTR + s * 32 + kg * 8];
            acc2[Nt] = __builtin_amdgcn_mfma_f32_16x16x32_bf16(w2[s], bfr, acc2[Nt], 0, 0, 0);
        }
    }
#pragma unroll
    for (int Nt = 0; Nt < 4; ++Nt) {
        int gy = y0 + Nt, gx = x0 + n15;
#pragma unroll
        for (int r = 0; r < 4; ++r) {
            int c = wv * 16 + hi4 + r;
            float v = fmaf(acc2[Nt][r], inv4[r], sh4[r]);
            out[((size_t)(b * 64 + c)) * 36864 + (size_t)gy * 192 + gx] = v > 0.f ? v : 0.f;
        }
    }
}

extern "C" void kernel_launch(void* const* d_in, const int* in_sizes, int n_in,
                              void* d_out, int out_size, void* d_ws, size_t ws_size,
                              hipStream_t stream) {
    float* out = (float*)d_out;

    unsigned short* f1 = (unsigned short*)d_ws;
    unsigned short* f2 = f1 + (size_t)4 * 64 * 36864;

    unsigned short* wfK = (unsigned short*)d_out + 18800640;
    unsigned short* wfQ = wfK + 36864;

    unsigned short* w2f = nullptr;
    if (ws_size >= 37748736ull + 20480ull) {
        w2f = (unsigned short*)((char*)d_ws + 37748736);
        prep_w2frag<<<1, 256, 0, stream>>>((const float*)d_in[14], w2f);
    }

    prep_wfrag<<<dim3(2), 256, 0, stream>>>(
        (const float*)d_in[2], (const float*)d_in[8], wfK, wfQ);

    dim3 cgrid(12, 24, 8);
    conv3x3_mfma_P<<<cgrid, 256, 0, stream>>>(
        (const float*)d_in[0], (const float*)d_in[1], wfK, wfQ,
        (const float*)d_in[3], (const float*)d_in[4], (const float*)d_in[5],
        (const float*)d_in[6], (const float*)d_in[7],
        (const float*)d_in[9], (const float*)d_in[10], (const float*)d_in[11],
        (const float*)d_in[12], (const float*)d_in[13],
        f1, f2);

    dim3 ggrid(12, 48, 4);
    corr_conv1x1_mfma<<<ggrid, 256, 0, stream>>>(
        f1, f2,
        (const float*)d_in[14], w2f,
        (const float*)d_in[15], (const float*)d_in[16],
        (const float*)d_in[17], (const float*)d_in[18], (const float*)d_in[19],
        out);
}

// Round 31
// 104.271 us; speedup vs baseline: 1.1823x; 1.1823x over previous
//
#include <hip/hip_runtime.h>

#define EPSf 1e-5f
#define NPAD 72     // win/f2w ci stride: 16B-aligned b128
#define CSTR 168    // cbuf row stride (corr)

typedef __attribute__((ext_vector_type(8))) short short8;
typedef __attribute__((ext_vector_type(4))) float f32x4;
typedef __attribute__((ext_vector_type(16))) float f32x16;

static __device__ __forceinline__ unsigned short f32_to_bf16(float f) {
    unsigned int u = __float_as_uint(f);
    unsigned int r = (u + 0x7FFFu + ((u >> 16) & 1u)) >> 16;
    return (unsigned short)r;
}
static __device__ __forceinline__ float bf16_to_f32(unsigned short h) {
    return __uint_as_float(((unsigned int)h) << 16);
}

// Merged prep: blocks 0,1 pack conv weights (32x32x16 B-frag order, r29-validated);
// block 2 packs corr W2 (GEMM2 A-frag order, r27-validated; skipped if dst null).
__global__ __launch_bounds__(256) void prep_all(
    const float* __restrict__ wK, const float* __restrict__ wQ,
    const float* __restrict__ qw,
    unsigned short* __restrict__ fK, unsigned short* __restrict__ fQ,
    unsigned short* __restrict__ w2f)
{
    const int t = threadIdx.x;
    if (blockIdx.x < 2) {
        const float* src = (blockIdx.x == 0) ? wK : wQ;
        unsigned short* dst = (blockIdx.x == 0) ? fK : fQ;
#pragma unroll
        for (int it = 0; it < 18; ++it) {
            int idx = t + it * 256;               // 0..4607
            int l = idx & 63, rest = idx >> 6;    // rest 0..71
            int s = rest % 36, nt = rest / 36;
            int tap = s >> 2, cig = s & 3;
            int cout = nt * 32 + (l & 31), khl = l >> 5;
            short8 v;
#pragma unroll
            for (int e = 0; e < 8; ++e) {
                int ci = cig * 16 + khl * 8 + e;
                ((unsigned short*)&v)[e] = f32_to_bf16(src[(size_t)cout * 576 + ci * 9 + tap]);
            }
            *(short8*)&dst[(size_t)idx * 8] = v;
        }
    } else {
        if (!w2f) return;
        const int wv = t >> 6, l = t & 63;
        const int n = l & 15, kg = l >> 4;
        const int cout = wv * 16 + n;
#pragma unroll
        for (int s = 0; s < 5; ++s) {
            short8 v;
#pragma unroll
            for (int e = 0; e < 8; ++e) {
                int k = s * 32 + kg * 8 + e;
                float w = 0.f;
                if (k < 81)                  w = qw[cout * 145 + k];
                else if (k >= 88 && k < 152) w = qw[cout * 145 + k - 7];
                ((unsigned short*)&v)[e] = f32_to_bf16(w);
            }
            *(short8*)&w2f[((wv * 5 + s) * 64 + l) * 8] = v;
        }
    }
}

// Both 3x3 convs, ONE dispatch, 32x32x16 MFMA core, ci-split 2-stage pipeline,
// XCD swizzle. EXACT r29 version (validated best: ~68us).
// Wave wv: nt = wv&1 (cout 32-half), mhalf = wv>>1 (px 64-half; 2 M-tiles of 32).
__global__ __launch_bounds__(256) void conv3x3_mfma_P(
    const float* __restrict__ fm1, const float* __restrict__ fm2,
    const unsigned short* __restrict__ wfK, const unsigned short* __restrict__ wfQ,
    const float* __restrict__ bK, const float* __restrict__ gK,
    const float* __restrict__ beK, const float* __restrict__ mK, const float* __restrict__ vK,
    const float* __restrict__ bQ, const float* __restrict__ gQ,
    const float* __restrict__ beQ, const float* __restrict__ mQ, const float* __restrict__ vQ,
    unsigned short* __restrict__ f1o, unsigned short* __restrict__ f2o)
{
    __shared__ unsigned short win[10 * 18 * NPAD];
    const int t  = threadIdx.x;
    // ---- XCD swizzle: nwg=2304=8*288, one (which,b) slice per XCD ----
    const int id  = blockIdx.x + 12 * (blockIdx.y + 24 * blockIdx.z);
    const int id2 = (id & 7) * 288 + (id >> 3);
    const int x0 = (id2 % 12) << 4;
    const int y0 = ((id2 / 12) % 24) << 3;
    const int zz = id2 / 288;
    const int b  = zz & 3, which = zz >> 2;

    const float* in = which ? fm2 : fm1;
    const unsigned short* wfrag = which ? wfQ : wfK;
    const float* bias = which ? bQ : bK;
    const float* bn_g = which ? gQ : gK;
    const float* bn_be = which ? beQ : beK;
    const float* bn_m = which ? mQ : mK;
    const float* bn_v = which ? vQ : vK;
    unsigned short* out = which ? f2o : f1o;
    const float* inb = in + (size_t)b * 64 * 36864;

    if (x0 == 0) {
        for (int i = t; i < 640; i += 256) {
            int ci = i & 63, row = i >> 6;
            win[(row * 18 + 0) * NPAD + ci] = 0;
        }
    } else if (x0 == 176) {
        for (int i = t; i < 640; i += 256) {
            int ci = i & 63, row = i >> 6;
            win[(row * 18 + 17) * NPAD + ci] = 0;
        }
    }

    const int gxs = (x0 == 0) ? 0 : ((x0 == 176) ? 168 : x0 - 4);
    const int wv = t >> 6, l = t & 63;
    const int nt = wv & 1, mhalf = wv >> 1;
    const int c31 = l & 31, khl = l >> 5;
    const int cout = nt * 32 + c31;
    const unsigned short* wf = wfrag + (size_t)nt * 36 * 512 + l * 8;

    const float inv = bn_g[cout] / sqrtf(bn_v[cout] + EPSf);
    const float sh  = (bias[cout] - bn_m[cout]) * inv + bn_be[cout];

    f32x16 acc0, acc1;
#pragma unroll
    for (int i = 0; i < 16; ++i) { acc0[i] = 0.f; acc1[i] = 0.f; }

    const int px0 = (mhalf * 2 + 0) * 32 + c31;
    const int px1 = (mhalf * 2 + 1) * 32 + c31;
    const int py0 = px0 >> 4, pxx0 = px0 & 15;
    const int py1 = px1 >> 4, pxx1 = px1 & 15;

    // ---- stage half 0: ci[0,32) ----
#pragma unroll
    for (int it = 0; it < 8; ++it) {
        int q = t + (it << 8);
        if (q < 1920) {
            int p = q / 6, j = q - p * 6;
            int ci = p & 31, row = p >> 5;
            int gy = y0 - 1 + row;
            bool rowok = (gy >= 0 && gy < 192);
            int gya = rowok ? gy : (gy < 0 ? 0 : 191);
            int gxa = gxs + j * 4;
            f32x4 v = *(const f32x4*)(inb + (size_t)ci * 36864 + gya * 192 + gxa);
#pragma unroll
            for (int e = 0; e < 4; ++e) {
                int col = gxa + e - (x0 - 1);
                if (col >= 0 && col < 18)
                    win[(row * 18 + col) * NPAD + ci] = f32_to_bf16(rowok ? v[e] : 0.f);
            }
        }
    }
    __syncthreads();

    // ---- issue half-1 staging (flies under phase-0 MFMAs via wave overlap) ----
#pragma unroll
    for (int it = 0; it < 8; ++it) {
        int q = t + (it << 8);
        if (q < 1920) {
            int p = q / 6, j = q - p * 6;
            int ci = 32 + (p & 31), row = p >> 5;
            int gy = y0 - 1 + row;
            bool rowok = (gy >= 0 && gy < 192);
            int gya = rowok ? gy : (gy < 0 ? 0 : 191);
            int gxa = gxs + j * 4;
            f32x4 v = *(const f32x4*)(inb + (size_t)ci * 36864 + gya * 192 + gxa);
#pragma unroll
            for (int e = 0; e < 4; ++e) {
                int col = gxa + e - (x0 - 1);
                if (col >= 0 && col < 18)
                    win[(row * 18 + col) * NPAD + ci] = f32_to_bf16(rowok ? v[e] : 0.f);
            }
        }
    }

    // ---- MFMA phase 0: cig in {0,1} (ci<32) ----
#pragma unroll
    for (int tap = 0; tap < 9; ++tap) {
#pragma unroll
        for (int cig = 0; cig < 2; ++cig) {
            int s = tap * 4 + cig;
            short8 bfr = *(const short8*)&wf[s * 512];
            int ky = tap / 3, kx = tap - ky * 3;
            int cb = cig * 16 + khl * 8;
            short8 a0 = *(const short8*)&win[((py0 + ky) * 18 + pxx0 + kx) * NPAD + cb];
            short8 a1 = *(const short8*)&win[((py1 + ky) * 18 + pxx1 + kx) * NPAD + cb];
            acc0 = __builtin_amdgcn_mfma_f32_32x32x16_bf16(a0, bfr, acc0, 0, 0, 0);
            acc1 = __builtin_amdgcn_mfma_f32_32x32x16_bf16(a1, bfr, acc1, 0, 0, 0);
        }
    }
    __syncthreads();

    // ---- MFMA phase 1: cig in {2,3} (ci>=32) ----
#pragma unroll
    for (int tap = 0; tap < 9; ++tap) {
#pragma unroll
        for (int cig = 2; cig < 4; ++cig) {
            int s = tap * 4 + cig;
            short8 bfr = *(const short8*)&wf[s * 512];
            int ky = tap / 3, kx = tap - ky * 3;
            int cb = cig * 16 + khl * 8;
            short8 a0 = *(const short8*)&win[((py0 + ky) * 18 + pxx0 + kx) * NPAD + cb];
            short8 a1 = *(const short8*)&win[((py1 + ky) * 18 + pxx1 + kx) * NPAD + cb];
            acc0 = __builtin_amdgcn_mfma_f32_32x32x16_bf16(a0, bfr, acc0, 0, 0, 0);
            acc1 = __builtin_amdgcn_mfma_f32_32x32x16_bf16(a1, bfr, acc1, 0, 0, 0);
        }
    }

    // ---- epilogue: D col = l&31 -> cout; row = (r&3)+8*(r>>2)+4*khl -> px ----
    const size_t pbase = (size_t)b * 36864;
#pragma unroll
    for (int mt2 = 0; mt2 < 2; ++mt2) {
#pragma unroll
        for (int r = 0; r < 16; ++r) {
            int rowm = (r & 3) + 8 * (r >> 2) + 4 * khl;
            int px = (mhalf * 2 + mt2) * 32 + rowm;
            int py = px >> 4, pxx = px & 15;
            float v = fmaf(mt2 ? acc1[r] : acc0[r], inv, sh);
            out[(pbase + (size_t)(y0 + py) * 192 + x0 + pxx) * 64 + cout] =
                f32_to_bf16(v > 0.f ? v : 0.f);
        }
    }
}

// Fused corr(R=4) + 1x1 conv — EXACT r28 version (validated, incl. XCD swizzle).
__global__ __launch_bounds__(256) void corr_conv1x1_mfma(
    const unsigned short* __restrict__ f1, const unsigned short* __restrict__ f2,
    const float* __restrict__ qw,
    const unsigned short* __restrict__ w2f,   // may be null
    const float* __restrict__ qb,
    const float* __restrict__ qg, const float* __restrict__ qbe,
    const float* __restrict__ qm, const float* __restrict__ qv,
    float* __restrict__ out)
{
    __shared__ unsigned short smem[20736 + 64 * CSTR];
    unsigned short* f2w  = smem;
    unsigned short* cbuf = smem + 20736;

    const int t  = threadIdx.x;
    const int id  = blockIdx.x + 12 * (blockIdx.y + 48 * blockIdx.z);
    const int id2 = (id & 7) * 288 + (id >> 3);
    const int x0 = (id2 % 12) << 4;
    const int y0 = ((id2 / 12) % 48) << 2;
    const int b  = id2 / 576;

    const int wv = t >> 6, l = t & 63;
    const int n15 = l & 15, kg = l >> 4, hi4 = kg << 2;
    const size_t pbase = (size_t)b * 36864;

#pragma unroll
    for (int i = 0; i < 9; ++i) {
        int q = t + (i << 8);
        int r = q / 192, rem = q - r * 192;
        int u = rem >> 3, j = rem & 7;
        int gy = y0 - 4 + r, gx = x0 - 4 + u;
        short8 v = {0, 0, 0, 0, 0, 0, 0, 0};
        if (gy >= 0 && gy < 192 && gx >= 0 && gx < 192)
            v = *(const short8*)&f2[(pbase + (size_t)gy * 192 + gx) * 64 + j * 8];
        *(short8*)&f2w[(r * 24 + u) * NPAD + j * 8] = v;
    }
#pragma unroll
    for (int i = 0; i < 2; ++i) {
        int q = t + (i << 8);
        int px = q >> 3, j = q & 7;
        int gy = y0 + (px >> 4), gx = x0 + (px & 15);
        short8 v = *(const short8*)&f1[(pbase + (size_t)gy * 192 + gx) * 64 + j * 8];
        *(short8*)&cbuf[px * CSTR + 88 + j * 8] = v;
    }
    if (t < 64) {
#pragma unroll
        for (int d = 81; d < 88; ++d)  cbuf[t * CSTR + d] = 0;
#pragma unroll
        for (int d = 152; d < 168; ++d) cbuf[t * CSTR + d] = 0;
    }

    short8 w2[5];
    if (w2f) {
#pragma unroll
        for (int s = 0; s < 5; ++s)
            w2[s] = *(const short8*)&w2f[((wv * 5 + s) * 64 + l) * 8];
    } else {
        const int cout_a = wv * 16 + n15;
#pragma unroll
        for (int s = 0; s < 5; ++s) {
            short8 v;
#pragma unroll
            for (int e = 0; e < 8; ++e) {
                int k = s * 32 + kg * 8 + e;
                float w = 0.f;
                if (k < 81)                  w = qw[cout_a * 145 + k];
                else if (k >= 88 && k < 152) w = qw[cout_a * 145 + k - 7];
                ((unsigned short*)&v)[e] = f32_to_bf16(w);
            }
            w2[s] = v;
        }
    }
    float inv4[4], sh4[4];
#pragma unroll
    for (int r = 0; r < 4; ++r) {
        int c = wv * 16 + hi4 + r;
        inv4[r] = qg[c] / sqrtf(qv[c] + EPSf);
        sh4[r]  = (qb[c] - qm[c]) * inv4[r] + qbe[c];
    }

    __syncthreads();

    const int ty = wv, tx = n15;
    short8 bfr0 = *(const short8*)&cbuf[(ty * 16 + n15) * CSTR + 88 + kg * 8];
    short8 bfr1 = *(const short8*)&cbuf[(ty * 16 + n15) * CSTR + 120 + kg * 8];
    const int rowb = (ty * 16 + tx) * CSTR;
#pragma unroll
    for (int Mt = 0; Mt < 14; ++Mt) {
        int row = ty * 24 + Mt * 16 + n15;
        short8 a0 = *(const short8*)&f2w[row * NPAD + kg * 8];
        short8 a1 = *(const short8*)&f2w[row * NPAD + 32 + kg * 8];
        f32x4 acc = (f32x4){0.f, 0.f, 0.f, 0.f};
        acc = __builtin_amdgcn_mfma_f32_16x16x32_bf16(a0, bfr0, acc, 0, 0, 0);
        acc = __builtin_amdgcn_mfma_f32_16x16x32_bf16(a1, bfr1, acc, 0, 0, 0);
#pragma unroll
        for (int r = 0; r < 4; ++r) {
            int m  = Mt * 16 + hi4 + r;
            int bb = m / 24;
            int u  = m - bb * 24;
            int a  = u - tx;
            if (m < 216 && a >= 0 && a <= 8)
                cbuf[rowb + a * 9 + bb] = f32_to_bf16(acc[r] * 0.125f);
        }
    }
    __syncthreads();

    f32x4 acc2[4];
#pragma unroll
    for (int Nt = 0; Nt < 4; ++Nt) {
        acc2[Nt] = (f32x4){0.f, 0.f, 0.f, 0.f};
#pragma unroll
        for (int s = 0; s < 5; ++s) {
            short8 bfr = *(const short8*)&cbuf[(Nt * 16 + n15) * CSTR + s * 32 + kg * 8];
            acc2[Nt] = __builtin_amdgcn_mfma_f32_16x16x32_bf16(w2[s], bfr, acc2[Nt], 0, 0, 0);
        }
    }
#pragma unroll
    for (int Nt = 0; Nt < 4; ++Nt) {
        int gy = y0 + Nt, gx = x0 + n15;
#pragma unroll
        for (int r = 0; r < 4; ++r) {
            int c = wv * 16 + hi4 + r;
            float v = fmaf(acc2[Nt][r], inv4[r], sh4[r]);
            out[((size_t)(b * 64 + c)) * 36864 + (size_t)gy * 192 + gx] = v > 0.f ? v : 0.f;
        }
    }
}

extern "C" void kernel_launch(void* const* d_in, const int* in_sizes, int n_in,
                              void* d_out, int out_size, void* d_ws, size_t ws_size,
                              hipStream_t stream) {
    float* out = (float*)d_out;

    unsigned short* f1 = (unsigned short*)d_ws;
    unsigned short* f2 = f1 + (size_t)4 * 64 * 36864;

    unsigned short* wfK = (unsigned short*)d_out + 18800640;
    unsigned short* wfQ = wfK + 36864;

    unsigned short* w2f = nullptr;
    if (ws_size >= 37748736ull + 20480ull)
        w2f = (unsigned short*)((char*)d_ws + 37748736);

    prep_all<<<dim3(3), 256, 0, stream>>>(
        (const float*)d_in[2], (const float*)d_in[8], (const float*)d_in[14],
        wfK, wfQ, w2f);

    dim3 cgrid(12, 24, 8);
    conv3x3_mfma_P<<<cgrid, 256, 0, stream>>>(
        (const float*)d_in[0], (const float*)d_in[1], wfK, wfQ,
        (const float*)d_in[3], (const float*)d_in[4], (const float*)d_in[5],
        (const float*)d_in[6], (const float*)d_in[7],
        (const float*)d_in[9], (const float*)d_in[10], (const float*)d_in[11],
        (const float*)d_in[12], (const float*)d_in[13],
        f1, f2);

    dim3 ggrid(12, 48, 4);
    corr_conv1x1_mfma<<<ggrid, 256, 0, stream>>>(
        f1, f2,
        (const float*)d_in[14], w2f,
        (const float*)d_in[15], (const float*)d_in[16],
        (const float*)d_in[17], (const float*)d_in[18], (const float*)d_in[19],
        out);
}

// Round 32
// 96.744 us; speedup vs baseline: 1.2743x; 1.0778x over previous
//
#include <hip/hip_runtime.h>

#define EPSf 1e-5f
#define NPAD 72     // win/f2w ci stride: 16B-aligned b128
#define CSTR 168    // cbuf row stride (corr)

typedef __attribute__((ext_vector_type(8))) short short8;
typedef __attribute__((ext_vector_type(4))) float f32x4;
typedef __attribute__((ext_vector_type(16))) float f32x16;

static __device__ __forceinline__ unsigned short f32_to_bf16(float f) {
    unsigned int u = __float_as_uint(f);
    unsigned int r = (u + 0x7FFFu + ((u >> 16) & 1u)) >> 16;
    return (unsigned short)r;
}
static __device__ __forceinline__ float bf16_to_f32(unsigned short h) {
    return __uint_as_float(((unsigned int)h) << 16);
}

// Merged prep: blocks 0,1 pack conv weights (32x32x16 B-frag order, r29-validated);
// block 2 packs corr W2 (GEMM2 A-frag order, r27-validated; skipped if dst null).
__global__ __launch_bounds__(256) void prep_all(
    const float* __restrict__ wK, const float* __restrict__ wQ,
    const float* __restrict__ qw,
    unsigned short* __restrict__ fK, unsigned short* __restrict__ fQ,
    unsigned short* __restrict__ w2f)
{
    const int t = threadIdx.x;
    if (blockIdx.x < 2) {
        const float* src = (blockIdx.x == 0) ? wK : wQ;
        unsigned short* dst = (blockIdx.x == 0) ? fK : fQ;
#pragma unroll
        for (int it = 0; it < 18; ++it) {
            int idx = t + it * 256;               // 0..4607
            int l = idx & 63, rest = idx >> 6;    // rest 0..71
            int s = rest % 36, nt = rest / 36;
            int tap = s >> 2, cig = s & 3;
            int cout = nt * 32 + (l & 31), khl = l >> 5;
            short8 v;
#pragma unroll
            for (int e = 0; e < 8; ++e) {
                int ci = cig * 16 + khl * 8 + e;
                ((unsigned short*)&v)[e] = f32_to_bf16(src[(size_t)cout * 576 + ci * 9 + tap]);
            }
            *(short8*)&dst[(size_t)idx * 8] = v;
        }
    } else {
        if (!w2f) return;
        const int wv = t >> 6, l = t & 63;
        const int n = l & 15, kg = l >> 4;
        const int cout = wv * 16 + n;
#pragma unroll
        for (int s = 0; s < 5; ++s) {
            short8 v;
#pragma unroll
            for (int e = 0; e < 8; ++e) {
                int k = s * 32 + kg * 8 + e;
                float w = 0.f;
                if (k < 81)                  w = qw[cout * 145 + k];
                else if (k >= 88 && k < 152) w = qw[cout * 145 + k - 7];
                ((unsigned short*)&v)[e] = f32_to_bf16(w);
            }
            *(short8*)&w2f[((wv * 5 + s) * 64 + l) * 8] = v;
        }
    }
}

// Both 3x3 convs, ONE dispatch, 32x32x16 MFMA core, ci-split 2-stage pipeline,
// XCD swizzle (r29/r31-validated). NEW: staging writes ci-PAIRS via ds_write_b32
// (ushort2 pack) — halves LDS write instructions and bank-conflict cycles.
__global__ __launch_bounds__(256) void conv3x3_mfma_P(
    const float* __restrict__ fm1, const float* __restrict__ fm2,
    const unsigned short* __restrict__ wfK, const unsigned short* __restrict__ wfQ,
    const float* __restrict__ bK, const float* __restrict__ gK,
    const float* __restrict__ beK, const float* __restrict__ mK, const float* __restrict__ vK,
    const float* __restrict__ bQ, const float* __restrict__ gQ,
    const float* __restrict__ beQ, const float* __restrict__ mQ, const float* __restrict__ vQ,
    unsigned short* __restrict__ f1o, unsigned short* __restrict__ f2o)
{
    __shared__ unsigned short win[10 * 18 * NPAD];
    const int t  = threadIdx.x;
    // ---- XCD swizzle: nwg=2304=8*288, one (which,b) slice per XCD ----
    const int id  = blockIdx.x + 12 * (blockIdx.y + 24 * blockIdx.z);
    const int id2 = (id & 7) * 288 + (id >> 3);
    const int x0 = (id2 % 12) << 4;
    const int y0 = ((id2 / 12) % 24) << 3;
    const int zz = id2 / 288;
    const int b  = zz & 3, which = zz >> 2;

    const float* in = which ? fm2 : fm1;
    const unsigned short* wfrag = which ? wfQ : wfK;
    const float* bias = which ? bQ : bK;
    const float* bn_g = which ? gQ : gK;
    const float* bn_be = which ? beQ : beK;
    const float* bn_m = which ? mQ : mK;
    const float* bn_v = which ? vQ : vK;
    unsigned short* out = which ? f2o : f1o;
    const float* inb = in + (size_t)b * 64 * 36864;

    if (x0 == 0) {
        for (int i = t; i < 640; i += 256) {
            int ci = i & 63, row = i >> 6;
            win[(row * 18 + 0) * NPAD + ci] = 0;
        }
    } else if (x0 == 176) {
        for (int i = t; i < 640; i += 256) {
            int ci = i & 63, row = i >> 6;
            win[(row * 18 + 17) * NPAD + ci] = 0;
        }
    }

    const int gxs = (x0 == 0) ? 0 : ((x0 == 176) ? 168 : x0 - 4);
    const int wv = t >> 6, l = t & 63;
    const int nt = wv & 1, mhalf = wv >> 1;
    const int c31 = l & 31, khl = l >> 5;
    const int cout = nt * 32 + c31;
    const unsigned short* wf = wfrag + (size_t)nt * 36 * 512 + l * 8;

    const float inv = bn_g[cout] / sqrtf(bn_v[cout] + EPSf);
    const float sh  = (bias[cout] - bn_m[cout]) * inv + bn_be[cout];

    f32x16 acc0, acc1;
#pragma unroll
    for (int i = 0; i < 16; ++i) { acc0[i] = 0.f; acc1[i] = 0.f; }

    const int px0 = (mhalf * 2 + 0) * 32 + c31;
    const int px1 = (mhalf * 2 + 1) * 32 + c31;
    const int py0 = px0 >> 4, pxx0 = px0 & 15;
    const int py1 = px1 >> 4, pxx1 = px1 & 15;

    // ---- stage half 0: ci[0,32) as 16 ci-pairs x 10 rows x 6 j = 960 items ----
#pragma unroll
    for (int it = 0; it < 4; ++it) {
        int q = t + (it << 8);
        if (q < 960) {
            int p = q / 6, j = q - p * 6;         // p: 0..159
            int cp = p & 15, row = p >> 4;        // ci-pair, row 0..9
            int ci = cp * 2;
            int gy = y0 - 1 + row;
            bool rowok = (gy >= 0 && gy < 192);
            int gya = rowok ? gy : (gy < 0 ? 0 : 191);
            int gxa = gxs + j * 4;
            f32x4 v0 = *(const f32x4*)(inb + (size_t)ci * 36864 + gya * 192 + gxa);
            f32x4 v1 = *(const f32x4*)(inb + (size_t)(ci + 1) * 36864 + gya * 192 + gxa);
#pragma unroll
            for (int e = 0; e < 4; ++e) {
                int col = gxa + e - (x0 - 1);
                if (col >= 0 && col < 18) {
                    unsigned int pk = (unsigned int)f32_to_bf16(rowok ? v0[e] : 0.f)
                                    | ((unsigned int)f32_to_bf16(rowok ? v1[e] : 0.f) << 16);
                    *(unsigned int*)&win[(row * 18 + col) * NPAD + ci] = pk;
                }
            }
        }
    }
    __syncthreads();

    // ---- issue half-1 staging (flies under phase-0 MFMAs via wave overlap) ----
#pragma unroll
    for (int it = 0; it < 4; ++it) {
        int q = t + (it << 8);
        if (q < 960) {
            int p = q / 6, j = q - p * 6;
            int cp = p & 15, row = p >> 4;
            int ci = 32 + cp * 2;
            int gy = y0 - 1 + row;
            bool rowok = (gy >= 0 && gy < 192);
            int gya = rowok ? gy : (gy < 0 ? 0 : 191);
            int gxa = gxs + j * 4;
            f32x4 v0 = *(const f32x4*)(inb + (size_t)ci * 36864 + gya * 192 + gxa);
            f32x4 v1 = *(const f32x4*)(inb + (size_t)(ci + 1) * 36864 + gya * 192 + gxa);
#pragma unroll
            for (int e = 0; e < 4; ++e) {
                int col = gxa + e - (x0 - 1);
                if (col >= 0 && col < 18) {
                    unsigned int pk = (unsigned int)f32_to_bf16(rowok ? v0[e] : 0.f)
                                    | ((unsigned int)f32_to_bf16(rowok ? v1[e] : 0.f) << 16);
                    *(unsigned int*)&win[(row * 18 + col) * NPAD + ci] = pk;
                }
            }
        }
    }

    // ---- MFMA phase 0: cig in {0,1} (ci<32) ----
#pragma unroll
    for (int tap = 0; tap < 9; ++tap) {
#pragma unroll
        for (int cig = 0; cig < 2; ++cig) {
            int s = tap * 4 + cig;
            short8 bfr = *(const short8*)&wf[s * 512];
            int ky = tap / 3, kx = tap - ky * 3;
            int cb = cig * 16 + khl * 8;
            short8 a0 = *(const short8*)&win[((py0 + ky) * 18 + pxx0 + kx) * NPAD + cb];
            short8 a1 = *(const short8*)&win[((py1 + ky) * 18 + pxx1 + kx) * NPAD + cb];
            acc0 = __builtin_amdgcn_mfma_f32_32x32x16_bf16(a0, bfr, acc0, 0, 0, 0);
            acc1 = __builtin_amdgcn_mfma_f32_32x32x16_bf16(a1, bfr, acc1, 0, 0, 0);
        }
    }
    __syncthreads();

    // ---- MFMA phase 1: cig in {2,3} (ci>=32) ----
#pragma unroll
    for (int tap = 0; tap < 9; ++tap) {
#pragma unroll
        for (int cig = 2; cig < 4; ++cig) {
            int s = tap * 4 + cig;
            short8 bfr = *(const short8*)&wf[s * 512];
            int ky = tap / 3, kx = tap - ky * 3;
            int cb = cig * 16 + khl * 8;
            short8 a0 = *(const short8*)&win[((py0 + ky) * 18 + pxx0 + kx) * NPAD + cb];
            short8 a1 = *(const short8*)&win[((py1 + ky) * 18 + pxx1 + kx) * NPAD + cb];
            acc0 = __builtin_amdgcn_mfma_f32_32x32x16_bf16(a0, bfr, acc0, 0, 0, 0);
            acc1 = __builtin_amdgcn_mfma_f32_32x32x16_bf16(a1, bfr, acc1, 0, 0, 0);
        }
    }

    // ---- epilogue: D col = l&31 -> cout; row = (r&3)+8*(r>>2)+4*khl -> px ----
    const size_t pbase = (size_t)b * 36864;
#pragma unroll
    for (int mt2 = 0; mt2 < 2; ++mt2) {
#pragma unroll
        for (int r = 0; r < 16; ++r) {
            int rowm = (r & 3) + 8 * (r >> 2) + 4 * khl;
            int px = (mhalf * 2 + mt2) * 32 + rowm;
            int py = px >> 4, pxx = px & 15;
            float v = fmaf(mt2 ? acc1[r] : acc0[r], inv, sh);
            out[(pbase + (size_t)(y0 + py) * 192 + x0 + pxx) * 64 + cout] =
                f32_to_bf16(v > 0.f ? v : 0.f);
        }
    }
}

// Fused corr(R=4) + 1x1 conv — EXACT r28 version (validated, incl. XCD swizzle).
__global__ __launch_bounds__(256) void corr_conv1x1_mfma(
    const unsigned short* __restrict__ f1, const unsigned short* __restrict__ f2,
    const float* __restrict__ qw,
    const unsigned short* __restrict__ w2f,   // may be null
    const float* __restrict__ qb,
    const float* __restrict__ qg, const float* __restrict__ qbe,
    const float* __restrict__ qm, const float* __restrict__ qv,
    float* __restrict__ out)
{
    __shared__ unsigned short smem[20736 + 64 * CSTR];
    unsigned short* f2w  = smem;
    unsigned short* cbuf = smem + 20736;

    const int t  = threadIdx.x;
    const int id  = blockIdx.x + 12 * (blockIdx.y + 48 * blockIdx.z);
    const int id2 = (id & 7) * 288 + (id >> 3);
    const int x0 = (id2 % 12) << 4;
    const int y0 = ((id2 / 12) % 48) << 2;
    const int b  = id2 / 576;

    const int wv = t >> 6, l = t & 63;
    const int n15 = l & 15, kg = l >> 4, hi4 = kg << 2;
    const size_t pbase = (size_t)b * 36864;

#pragma unroll
    for (int i = 0; i < 9; ++i) {
        int q = t + (i << 8);
        int r = q / 192, rem = q - r * 192;
        int u = rem >> 3, j = rem & 7;
        int gy = y0 - 4 + r, gx = x0 - 4 + u;
        short8 v = {0, 0, 0, 0, 0, 0, 0, 0};
        if (gy >= 0 && gy < 192 && gx >= 0 && gx < 192)
            v = *(const short8*)&f2[(pbase + (size_t)gy * 192 + gx) * 64 + j * 8];
        *(short8*)&f2w[(r * 24 + u) * NPAD + j * 8] = v;
    }
#pragma unroll
    for (int i = 0; i < 2; ++i) {
        int q = t + (i << 8);
        int px = q >> 3, j = q & 7;
        int gy = y0 + (px >> 4), gx = x0 + (px & 15);
        short8 v = *(const short8*)&f1[(pbase + (size_t)gy * 192 + gx) * 64 + j * 8];
        *(short8*)&cbuf[px * CSTR + 88 + j * 8] = v;
    }
    if (t < 64) {
#pragma unroll
        for (int d = 81; d < 88; ++d)  cbuf[t * CSTR + d] = 0;
#pragma unroll
        for (int d = 152; d < 168; ++d) cbuf[t * CSTR + d] = 0;
    }

    short8 w2[5];
    if (w2f) {
#pragma unroll
        for (int s = 0; s < 5; ++s)
            w2[s] = *(const short8*)&w2f[((wv * 5 + s) * 64 + l) * 8];
    } else {
        const int cout_a = wv * 16 + n15;
#pragma unroll
        for (int s = 0; s < 5; ++s) {
            short8 v;
#pragma unroll
            for (int e = 0; e < 8; ++e) {
                int k = s * 32 + kg * 8 + e;
                float w = 0.f;
                if (k < 81)                  w = qw[cout_a * 145 + k];
                else if (k >= 88 && k < 152) w = qw[cout_a * 145 + k - 7];
                ((unsigned short*)&v)[e] = f32_to_bf16(w);
            }
            w2[s] = v;
        }
    }
    float inv4[4], sh4[4];
#pragma unroll
    for (int r = 0; r < 4; ++r) {
        int c = wv * 16 + hi4 + r;
        inv4[r] = qg[c] / sqrtf(qv[c] + EPSf);
        sh4[r]  = (qb[c] - qm[c]) * inv4[r] + qbe[c];
    }

    __syncthreads();

    const int ty = wv, tx = n15;
    short8 bfr0 = *(const short8*)&cbuf[(ty * 16 + n15) * CSTR + 88 + kg * 8];
    short8 bfr1 = *(const short8*)&cbuf[(ty * 16 + n15) * CSTR + 120 + kg * 8];
    const int rowb = (ty * 16 + tx) * CSTR;
#pragma unroll
    for (int Mt = 0; Mt < 14; ++Mt) {
        int row = ty * 24 + Mt * 16 + n15;
        short8 a0 = *(const short8*)&f2w[row * NPAD + kg * 8];
        short8 a1 = *(const short8*)&f2w[row * NPAD + 32 + kg * 8];
        f32x4 acc = (f32x4){0.f, 0.f, 0.f, 0.f};
        acc = __builtin_amdgcn_mfma_f32_16x16x32_bf16(a0, bfr0, acc, 0, 0, 0);
        acc = __builtin_amdgcn_mfma_f32_16x16x32_bf16(a1, bfr1, acc, 0, 0, 0);
#pragma unroll
        for (int r = 0; r < 4; ++r) {
            int m  = Mt * 16 + hi4 + r;
            int bb = m / 24;
            int u  = m - bb * 24;
            int a  = u - tx;
            if (m < 216 && a >= 0 && a <= 8)
                cbuf[rowb + a * 9 + bb] = f32_to_bf16(acc[r] * 0.125f);
        }
    }
    __syncthreads();

    f32x4 acc2[4];
#pragma unroll
    for (int Nt = 0; Nt < 4; ++Nt) {
        acc2[Nt] = (f32x4){0.f, 0.f, 0.f, 0.f};
#pragma unroll
        for (int s = 0; s < 5; ++s) {
            short8 bfr = *(const short8*)&cbuf[(Nt * 16 + n15) * CSTR + s * 32 + kg * 8];
            acc2[Nt] = __builtin_amdgcn_mfma_f32_16x16x32_bf16(w2[s], bfr, acc2[Nt], 0, 0, 0);
        }
    }
#pragma unroll
    for (int Nt = 0; Nt < 4; ++Nt) {
        int gy = y0 + Nt, gx = x0 + n15;
#pragma unroll
        for (int r = 0; r < 4; ++r) {
            int c = wv * 16 + hi4 + r;
            float v = fmaf(acc2[Nt][r], inv4[r], sh4[r]);
            out[((size_t)(b * 64 + c)) * 36864 + (size_t)gy * 192 + gx] = v > 0.f ? v : 0.f;
        }
    }
}

extern "C" void kernel_launch(void* const* d_in, const int* in_sizes, int n_in,
                              void* d_out, int out_size, void* d_ws, size_t ws_size,
                              hipStream_t stream) {
    float* out = (float*)d_out;

    unsigned short* f1 = (unsigned short*)d_ws;
    unsigned short* f2 = f1 + (size_t)4 * 64 * 36864;

    unsigned short* wfK = (unsigned short*)d_out + 18800640;
    unsigned short* wfQ = wfK + 36864;

    unsigned short* w2f = nullptr;
    if (ws_size >= 37748736ull + 20480ull)
        w2f = (unsigned short*)((char*)d_ws + 37748736);

    prep_all<<<dim3(3), 256, 0, stream>>>(
        (const float*)d_in[2], (const float*)d_in[8], (const float*)d_in[14],
        wfK, wfQ, w2f);

    dim3 cgrid(12, 24, 8);
    conv3x3_mfma_P<<<cgrid, 256, 0, stream>>>(
        (const float*)d_in[0], (const float*)d_in[1], wfK, wfQ,
        (const float*)d_in[3], (const float*)d_in[4], (const float*)d_in[5],
        (const float*)d_in[6], (const float*)d_in[7],
        (const float*)d_in[9], (const float*)d_in[10], (const float*)d_in[11],
        (const float*)d_in[12], (const float*)d_in[13],
        f1, f2);

    dim3 ggrid(12, 48, 4);
    corr_conv1x1_mfma<<<ggrid, 256, 0, stream>>>(
        f1, f2,
        (const float*)d_in[14], w2f,
        (const float*)d_in[15], (const float*)d_in[16],
        (const float*)d_in[17], (const float*)d_in[18], (const float*)d_in[19],
        out);
}

// Round 33
// 94.794 us; speedup vs baseline: 1.3005x; 1.0206x over previous
//
#include <hip/hip_runtime.h>

#define EPSf 1e-5f
#define NPAD 72     // win/f2w ci stride: 16B-aligned b128
#define CSTR 168    // cbuf row stride (corr)

typedef __attribute__((ext_vector_type(8))) short short8;
typedef __attribute__((ext_vector_type(4))) short short4v;
typedef __attribute__((ext_vector_type(4))) float f32x4;
typedef __attribute__((ext_vector_type(16))) float f32x16;

static __device__ __forceinline__ unsigned short f32_to_bf16(float f) {
    unsigned int u = __float_as_uint(f);
    unsigned int r = (u + 0x7FFFu + ((u >> 16) & 1u)) >> 16;
    return (unsigned short)r;
}
static __device__ __forceinline__ float bf16_to_f32(unsigned short h) {
    return __uint_as_float(((unsigned int)h) << 16);
}

// Merged prep: blocks 0,1 pack conv weights (32x32x16 B-frag order, r29-validated);
// block 2 packs corr W2 (GEMM2 A-frag order, r27-validated; skipped if dst null).
__global__ __launch_bounds__(256) void prep_all(
    const float* __restrict__ wK, const float* __restrict__ wQ,
    const float* __restrict__ qw,
    unsigned short* __restrict__ fK, unsigned short* __restrict__ fQ,
    unsigned short* __restrict__ w2f)
{
    const int t = threadIdx.x;
    if (blockIdx.x < 2) {
        const float* src = (blockIdx.x == 0) ? wK : wQ;
        unsigned short* dst = (blockIdx.x == 0) ? fK : fQ;
#pragma unroll
        for (int it = 0; it < 18; ++it) {
            int idx = t + it * 256;               // 0..4607
            int l = idx & 63, rest = idx >> 6;    // rest 0..71
            int s = rest % 36, nt = rest / 36;
            int tap = s >> 2, cig = s & 3;
            int cout = nt * 32 + (l & 31), khl = l >> 5;
            short8 v;
#pragma unroll
            for (int e = 0; e < 8; ++e) {
                int ci = cig * 16 + khl * 8 + e;
                ((unsigned short*)&v)[e] = f32_to_bf16(src[(size_t)cout * 576 + ci * 9 + tap]);
            }
            *(short8*)&dst[(size_t)idx * 8] = v;
        }
    } else {
        if (!w2f) return;
        const int wv = t >> 6, l = t & 63;
        const int n = l & 15, kg = l >> 4;
        const int cout = wv * 16 + n;
#pragma unroll
        for (int s = 0; s < 5; ++s) {
            short8 v;
#pragma unroll
            for (int e = 0; e < 8; ++e) {
                int k = s * 32 + kg * 8 + e;
                float w = 0.f;
                if (k < 81)                  w = qw[cout * 145 + k];
                else if (k >= 88 && k < 152) w = qw[cout * 145 + k - 7];
                ((unsigned short*)&v)[e] = f32_to_bf16(w);
            }
            *(short8*)&w2f[((wv * 5 + s) * 64 + l) * 8] = v;
        }
    }
}

// Both 3x3 convs, ONE dispatch, 32x32x16 MFMA core, ci-split 2-stage pipeline,
// XCD swizzle (r29/r31-validated). r32: paired staging writes. NEW (r33):
// ci-QUAD staging — 4 planes packed per item, ds_write_b64 (16 writes/thread).
__global__ __launch_bounds__(256) void conv3x3_mfma_P(
    const float* __restrict__ fm1, const float* __restrict__ fm2,
    const unsigned short* __restrict__ wfK, const unsigned short* __restrict__ wfQ,
    const float* __restrict__ bK, const float* __restrict__ gK,
    const float* __restrict__ beK, const float* __restrict__ mK, const float* __restrict__ vK,
    const float* __restrict__ bQ, const float* __restrict__ gQ,
    const float* __restrict__ beQ, const float* __restrict__ mQ, const float* __restrict__ vQ,
    unsigned short* __restrict__ f1o, unsigned short* __restrict__ f2o)
{
    __shared__ unsigned short win[10 * 18 * NPAD];
    const int t  = threadIdx.x;
    // ---- XCD swizzle: nwg=2304=8*288, one (which,b) slice per XCD ----
    const int id  = blockIdx.x + 12 * (blockIdx.y + 24 * blockIdx.z);
    const int id2 = (id & 7) * 288 + (id >> 3);
    const int x0 = (id2 % 12) << 4;
    const int y0 = ((id2 / 12) % 24) << 3;
    const int zz = id2 / 288;
    const int b  = zz & 3, which = zz >> 2;

    const float* in = which ? fm2 : fm1;
    const unsigned short* wfrag = which ? wfQ : wfK;
    const float* bias = which ? bQ : bK;
    const float* bn_g = which ? gQ : gK;
    const float* bn_be = which ? beQ : beK;
    const float* bn_m = which ? mQ : mK;
    const float* bn_v = which ? vQ : vK;
    unsigned short* out = which ? f2o : f1o;
    const float* inb = in + (size_t)b * 64 * 36864;

    if (x0 == 0) {
        for (int i = t; i < 640; i += 256) {
            int ci = i & 63, row = i >> 6;
            win[(row * 18 + 0) * NPAD + ci] = 0;
        }
    } else if (x0 == 176) {
        for (int i = t; i < 640; i += 256) {
            int ci = i & 63, row = i >> 6;
            win[(row * 18 + 17) * NPAD + ci] = 0;
        }
    }

    const int gxs = (x0 == 0) ? 0 : ((x0 == 176) ? 168 : x0 - 4);
    const int wv = t >> 6, l = t & 63;
    const int nt = wv & 1, mhalf = wv >> 1;
    const int c31 = l & 31, khl = l >> 5;
    const int cout = nt * 32 + c31;
    const unsigned short* wf = wfrag + (size_t)nt * 36 * 512 + l * 8;

    const float inv = bn_g[cout] / sqrtf(bn_v[cout] + EPSf);
    const float sh  = (bias[cout] - bn_m[cout]) * inv + bn_be[cout];

    f32x16 acc0, acc1;
#pragma unroll
    for (int i = 0; i < 16; ++i) { acc0[i] = 0.f; acc1[i] = 0.f; }

    const int px0 = (mhalf * 2 + 0) * 32 + c31;
    const int px1 = (mhalf * 2 + 1) * 32 + c31;
    const int py0 = px0 >> 4, pxx0 = px0 & 15;
    const int py1 = px1 >> 4, pxx1 = px1 & 15;

    // ---- stage half 0: ci[0,32) as 8 ci-quads x 10 rows x 6 j = 480 items ----
#pragma unroll
    for (int it = 0; it < 2; ++it) {
        int q = t + (it << 8);
        if (q < 480) {
            int p = q / 6, j = q - p * 6;         // p: 0..79
            int cq = p & 7, row = p >> 3;         // ci-quad, row 0..9
            int ci = cq * 4;
            int gy = y0 - 1 + row;
            bool rowok = (gy >= 0 && gy < 192);
            int gya = rowok ? gy : (gy < 0 ? 0 : 191);
            int gxa = gxs + j * 4;
            const float* rp = inb + (size_t)ci * 36864 + gya * 192 + gxa;
            f32x4 v0 = *(const f32x4*)(rp);
            f32x4 v1 = *(const f32x4*)(rp + 36864);
            f32x4 v2 = *(const f32x4*)(rp + 2 * 36864);
            f32x4 v3 = *(const f32x4*)(rp + 3 * 36864);
#pragma unroll
            for (int e = 0; e < 4; ++e) {
                int col = gxa + e - (x0 - 1);
                if (col >= 0 && col < 18) {
                    short4v pk;
                    ((unsigned short*)&pk)[0] = f32_to_bf16(rowok ? v0[e] : 0.f);
                    ((unsigned short*)&pk)[1] = f32_to_bf16(rowok ? v1[e] : 0.f);
                    ((unsigned short*)&pk)[2] = f32_to_bf16(rowok ? v2[e] : 0.f);
                    ((unsigned short*)&pk)[3] = f32_to_bf16(rowok ? v3[e] : 0.f);
                    *(short4v*)&win[(row * 18 + col) * NPAD + ci] = pk;
                }
            }
        }
    }
    __syncthreads();

    // ---- issue half-1 staging (flies under phase-0 MFMAs via wave overlap) ----
#pragma unroll
    for (int it = 0; it < 2; ++it) {
        int q = t + (it << 8);
        if (q < 480) {
            int p = q / 6, j = q - p * 6;
            int cq = p & 7, row = p >> 3;
            int ci = 32 + cq * 4;
            int gy = y0 - 1 + row;
            bool rowok = (gy >= 0 && gy < 192);
            int gya = rowok ? gy : (gy < 0 ? 0 : 191);
            int gxa = gxs + j * 4;
            const float* rp = inb + (size_t)ci * 36864 + gya * 192 + gxa;
            f32x4 v0 = *(const f32x4*)(rp);
            f32x4 v1 = *(const f32x4*)(rp + 36864);
            f32x4 v2 = *(const f32x4*)(rp + 2 * 36864);
            f32x4 v3 = *(const f32x4*)(rp + 3 * 36864);
#pragma unroll
            for (int e = 0; e < 4; ++e) {
                int col = gxa + e - (x0 - 1);
                if (col >= 0 && col < 18) {
                    short4v pk;
                    ((unsigned short*)&pk)[0] = f32_to_bf16(rowok ? v0[e] : 0.f);
                    ((unsigned short*)&pk)[1] = f32_to_bf16(rowok ? v1[e] : 0.f);
                    ((unsigned short*)&pk)[2] = f32_to_bf16(rowok ? v2[e] : 0.f);
                    ((unsigned short*)&pk)[3] = f32_to_bf16(rowok ? v3[e] : 0.f);
                    *(short4v*)&win[(row * 18 + col) * NPAD + ci] = pk;
                }
            }
        }
    }

    // ---- MFMA phase 0: cig in {0,1} (ci<32) ----
#pragma unroll
    for (int tap = 0; tap < 9; ++tap) {
#pragma unroll
        for (int cig = 0; cig < 2; ++cig) {
            int s = tap * 4 + cig;
            short8 bfr = *(const short8*)&wf[s * 512];
            int ky = tap / 3, kx = tap - ky * 3;
            int cb = cig * 16 + khl * 8;
            short8 a0 = *(const short8*)&win[((py0 + ky) * 18 + pxx0 + kx) * NPAD + cb];
            short8 a1 = *(const short8*)&win[((py1 + ky) * 18 + pxx1 + kx) * NPAD + cb];
            acc0 = __builtin_amdgcn_mfma_f32_32x32x16_bf16(a0, bfr, acc0, 0, 0, 0);
            acc1 = __builtin_amdgcn_mfma_f32_32x32x16_bf16(a1, bfr, acc1, 0, 0, 0);
        }
    }
    __syncthreads();

    // ---- MFMA phase 1: cig in {2,3} (ci>=32) ----
#pragma unroll
    for (int tap = 0; tap < 9; ++tap) {
#pragma unroll
        for (int cig = 2; cig < 4; ++cig) {
            int s = tap * 4 + cig;
            short8 bfr = *(const short8*)&wf[s * 512];
            int ky = tap / 3, kx = tap - ky * 3;
            int cb = cig * 16 + khl * 8;
            short8 a0 = *(const short8*)&win[((py0 + ky) * 18 + pxx0 + kx) * NPAD + cb];
            short8 a1 = *(const short8*)&win[((py1 + ky) * 18 + pxx1 + kx) * NPAD + cb];
            acc0 = __builtin_amdgcn_mfma_f32_32x32x16_bf16(a0, bfr, acc0, 0, 0, 0);
            acc1 = __builtin_amdgcn_mfma_f32_32x32x16_bf16(a1, bfr, acc1, 0, 0, 0);
        }
    }

    // ---- epilogue: D col = l&31 -> cout; row = (r&3)+8*(r>>2)+4*khl -> px ----
    const size_t pbase = (size_t)b * 36864;
#pragma unroll
    for (int mt2 = 0; mt2 < 2; ++mt2) {
#pragma unroll
        for (int r = 0; r < 16; ++r) {
            int rowm = (r & 3) + 8 * (r >> 2) + 4 * khl;
            int px = (mhalf * 2 + mt2) * 32 + rowm;
            int py = px >> 4, pxx = px & 15;
            float v = fmaf(mt2 ? acc1[r] : acc0[r], inv, sh);
            out[(pbase + (size_t)(y0 + py) * 192 + x0 + pxx) * 64 + cout] =
                f32_to_bf16(v > 0.f ? v : 0.f);
        }
    }
}

// Fused corr(R=4) + 1x1 conv — EXACT r28 version (validated, incl. XCD swizzle).
__global__ __launch_bounds__(256) void corr_conv1x1_mfma(
    const unsigned short* __restrict__ f1, const unsigned short* __restrict__ f2,
    const float* __restrict__ qw,
    const unsigned short* __restrict__ w2f,   // may be null
    const float* __restrict__ qb,
    const float* __restrict__ qg, const float* __restrict__ qbe,
    const float* __restrict__ qm, const float* __restrict__ qv,
    float* __restrict__ out)
{
    __shared__ unsigned short smem[20736 + 64 * CSTR];
    unsigned short* f2w  = smem;
    unsigned short* cbuf = smem + 20736;

    const int t  = threadIdx.x;
    const int id  = blockIdx.x + 12 * (blockIdx.y + 48 * blockIdx.z);
    const int id2 = (id & 7) * 288 + (id >> 3);
    const int x0 = (id2 % 12) << 4;
    const int y0 = ((id2 / 12) % 48) << 2;
    const int b  = id2 / 576;

    const int wv = t >> 6, l = t & 63;
    const int n15 = l & 15, kg = l >> 4, hi4 = kg << 2;
    const size_t pbase = (size_t)b * 36864;

#pragma unroll
    for (int i = 0; i < 9; ++i) {
        int q = t + (i << 8);
        int r = q / 192, rem = q - r * 192;
        int u = rem >> 3, j = rem & 7;
        int gy = y0 - 4 + r, gx = x0 - 4 + u;
        short8 v = {0, 0, 0, 0, 0, 0, 0, 0};
        if (gy >= 0 && gy < 192 && gx >= 0 && gx < 192)
            v = *(const short8*)&f2[(pbase + (size_t)gy * 192 + gx) * 64 + j * 8];
        *(short8*)&f2w[(r * 24 + u) * NPAD + j * 8] = v;
    }
#pragma unroll
    for (int i = 0; i < 2; ++i) {
        int q = t + (i << 8);
        int px = q >> 3, j = q & 7;
        int gy = y0 + (px >> 4), gx = x0 + (px & 15);
        short8 v = *(const short8*)&f1[(pbase + (size_t)gy * 192 + gx) * 64 + j * 8];
        *(short8*)&cbuf[px * CSTR + 88 + j * 8] = v;
    }
    if (t < 64) {
#pragma unroll
        for (int d = 81; d < 88; ++d)  cbuf[t * CSTR + d] = 0;
#pragma unroll
        for (int d = 152; d < 168; ++d) cbuf[t * CSTR + d] = 0;
    }

    short8 w2[5];
    if (w2f) {
#pragma unroll
        for (int s = 0; s < 5; ++s)
            w2[s] = *(const short8*)&w2f[((wv * 5 + s) * 64 + l) * 8];
    } else {
        const int cout_a = wv * 16 + n15;
#pragma unroll
        for (int s = 0; s < 5; ++s) {
            short8 v;
#pragma unroll
            for (int e = 0; e < 8; ++e) {
                int k = s * 32 + kg * 8 + e;
                float w = 0.f;
                if (k < 81)                  w = qw[cout_a * 145 + k];
                else if (k >= 88 && k < 152) w = qw[cout_a * 145 + k - 7];
                ((unsigned short*)&v)[e] = f32_to_bf16(w);
            }
            w2[s] = v;
        }
    }
    float inv4[4], sh4[4];
#pragma unroll
    for (int r = 0; r < 4; ++r) {
        int c = wv * 16 + hi4 + r;
        inv4[r] = qg[c] / sqrtf(qv[c] + EPSf);
        sh4[r]  = (qb[c] - qm[c]) * inv4[r] + qbe[c];
    }

    __syncthreads();

    const int ty = wv, tx = n15;
    short8 bfr0 = *(const short8*)&cbuf[(ty * 16 + n15) * CSTR + 88 + kg * 8];
    short8 bfr1 = *(const short8*)&cbuf[(ty * 16 + n15) * CSTR + 120 + kg * 8];
    const int rowb = (ty * 16 + tx) * CSTR;
#pragma unroll
    for (int Mt = 0; Mt < 14; ++Mt) {
        int row = ty * 24 + Mt * 16 + n15;
        short8 a0 = *(const short8*)&f2w[row * NPAD + kg * 8];
        short8 a1 = *(const short8*)&f2w[row * NPAD + 32 + kg * 8];
        f32x4 acc = (f32x4){0.f, 0.f, 0.f, 0.f};
        acc = __builtin_amdgcn_mfma_f32_16x16x32_bf16(a0, bfr0, acc, 0, 0, 0);
        acc = __builtin_amdgcn_mfma_f32_16x16x32_bf16(a1, bfr1, acc, 0, 0, 0);
#pragma unroll
        for (int r = 0; r < 4; ++r) {
            int m  = Mt * 16 + hi4 + r;
            int bb = m / 24;
            int u  = m - bb * 24;
            int a  = u - tx;
            if (m < 216 && a >= 0 && a <= 8)
                cbuf[rowb + a * 9 + bb] = f32_to_bf16(acc[r] * 0.125f);
        }
    }
    __syncthreads();

    f32x4 acc2[4];
#pragma unroll
    for (int Nt = 0; Nt < 4; ++Nt) {
        acc2[Nt] = (f32x4){0.f, 0.f, 0.f, 0.f};
#pragma unroll
        for (int s = 0; s < 5; ++s) {
            short8 bfr = *(const short8*)&cbuf[(Nt * 16 + n15) * CSTR + s * 32 + kg * 8];
            acc2[Nt] = __builtin_amdgcn_mfma_f32_16x16x32_bf16(w2[s], bfr, acc2[Nt], 0, 0, 0);
        }
    }
#pragma unroll
    for (int Nt = 0; Nt < 4; ++Nt) {
        int gy = y0 + Nt, gx = x0 + n15;
#pragma unroll
        for (int r = 0; r < 4; ++r) {
            int c = wv * 16 + hi4 + r;
            float v = fmaf(acc2[Nt][r], inv4[r], sh4[r]);
            out[((size_t)(b * 64 + c)) * 36864 + (size_t)gy * 192 + gx] = v > 0.f ? v : 0.f;
        }
    }
}

extern "C" void kernel_launch(void* const* d_in, const int* in_sizes, int n_in,
                              void* d_out, int out_size, void* d_ws, size_t ws_size,
                              hipStream_t stream) {
    float* out = (float*)d_out;

    unsigned short* f1 = (unsigned short*)d_ws;
    unsigned short* f2 = f1 + (size_t)4 * 64 * 36864;

    unsigned short* wfK = (unsigned short*)d_out + 18800640;
    unsigned short* wfQ = wfK + 36864;

    unsigned short* w2f = nullptr;
    if (ws_size >= 37748736ull + 20480ull)
        w2f = (unsigned short*)((char*)d_ws + 37748736);

    prep_all<<<dim3(3), 256, 0, stream>>>(
        (const float*)d_in[2], (const float*)d_in[8], (const float*)d_in[14],
        wfK, wfQ, w2f);

    dim3 cgrid(12, 24, 8);
    conv3x3_mfma_P<<<cgrid, 256, 0, stream>>>(
        (const float*)d_in[0], (const float*)d_in[1], wfK, wfQ,
        (const float*)d_in[3], (const float*)d_in[4], (const float*)d_in[5],
        (const float*)d_in[6], (const float*)d_in[7],
        (const float*)d_in[9], (const float*)d_in[10], (const float*)d_in[11],
        (const float*)d_in[12], (const float*)d_in[13],
        f1, f2);

    dim3 ggrid(12, 48, 4);
    corr_conv1x1_mfma<<<ggrid, 256, 0, stream>>>(
        f1, f2,
        (const float*)d_in[14], w2f,
        (const float*)d_in[15], (const float*)d_in[16],
        (const float*)d_in[17], (const float*)d_in[18], (const float*)d_in[19],
        out);
}

// Round 34
// 94.391 us; speedup vs baseline: 1.3060x; 1.0043x over previous
//
#include <hip/hip_runtime.h>

#define EPSf 1e-5f
#define NPAD 72     // win/f2w ci stride: 16B-aligned b128
#define CSTR 168    // cbuf row stride (corr)

typedef __attribute__((ext_vector_type(8))) short short8;
typedef __attribute__((ext_vector_type(4))) short short4v;
typedef __attribute__((ext_vector_type(4))) float f32x4;
typedef __attribute__((ext_vector_type(16))) float f32x16;

static __device__ __forceinline__ unsigned short f32_to_bf16(float f) {
    unsigned int u = __float_as_uint(f);
    unsigned int r = (u + 0x7FFFu + ((u >> 16) & 1u)) >> 16;
    return (unsigned short)r;
}
static __device__ __forceinline__ float bf16_to_f32(unsigned short h) {
    return __uint_as_float(((unsigned int)h) << 16);
}

// Merged prep: blocks 0,1 pack conv weights (32x32x16 B-frag order, r29-validated);
// block 2 packs corr W2 (GEMM2 A-frag order, r27-validated; skipped if dst null).
__global__ __launch_bounds__(256) void prep_all(
    const float* __restrict__ wK, const float* __restrict__ wQ,
    const float* __restrict__ qw,
    unsigned short* __restrict__ fK, unsigned short* __restrict__ fQ,
    unsigned short* __restrict__ w2f)
{
    const int t = threadIdx.x;
    if (blockIdx.x < 2) {
        const float* src = (blockIdx.x == 0) ? wK : wQ;
        unsigned short* dst = (blockIdx.x == 0) ? fK : fQ;
#pragma unroll
        for (int it = 0; it < 18; ++it) {
            int idx = t + it * 256;               // 0..4607
            int l = idx & 63, rest = idx >> 6;    // rest 0..71
            int s = rest % 36, nt = rest / 36;
            int tap = s >> 2, cig = s & 3;
            int cout = nt * 32 + (l & 31), khl = l >> 5;
            short8 v;
#pragma unroll
            for (int e = 0; e < 8; ++e) {
                int ci = cig * 16 + khl * 8 + e;
                ((unsigned short*)&v)[e] = f32_to_bf16(src[(size_t)cout * 576 + ci * 9 + tap]);
            }
            *(short8*)&dst[(size_t)idx * 8] = v;
        }
    } else {
        if (!w2f) return;
        const int wv = t >> 6, l = t & 63;
        const int n = l & 15, kg = l >> 4;
        const int cout = wv * 16 + n;
#pragma unroll
        for (int s = 0; s < 5; ++s) {
            short8 v;
#pragma unroll
            for (int e = 0; e < 8; ++e) {
                int k = s * 32 + kg * 8 + e;
                float w = 0.f;
                if (k < 81)                  w = qw[cout * 145 + k];
                else if (k >= 88 && k < 152) w = qw[cout * 145 + k - 7];
                ((unsigned short*)&v)[e] = f32_to_bf16(w);
            }
            *(short8*)&w2f[((wv * 5 + s) * 64 + l) * 8] = v;
        }
    }
}

// Both 3x3 convs, ONE dispatch, 32x32x16 MFMA core, ci-split 2-stage pipeline,
// XCD swizzle (r29/r31-validated). NEW (r34): ci-OCT staging — 8 planes packed
// per item, ds_write_b128 (8 writes/thread, single pass of 240 items/half).
__global__ __launch_bounds__(256) void conv3x3_mfma_P(
    const float* __restrict__ fm1, const float* __restrict__ fm2,
    const unsigned short* __restrict__ wfK, const unsigned short* __restrict__ wfQ,
    const float* __restrict__ bK, const float* __restrict__ gK,
    const float* __restrict__ beK, const float* __restrict__ mK, const float* __restrict__ vK,
    const float* __restrict__ bQ, const float* __restrict__ gQ,
    const float* __restrict__ beQ, const float* __restrict__ mQ, const float* __restrict__ vQ,
    unsigned short* __restrict__ f1o, unsigned short* __restrict__ f2o)
{
    __shared__ unsigned short win[10 * 18 * NPAD];
    const int t  = threadIdx.x;
    // ---- XCD swizzle: nwg=2304=8*288, one (which,b) slice per XCD ----
    const int id  = blockIdx.x + 12 * (blockIdx.y + 24 * blockIdx.z);
    const int id2 = (id & 7) * 288 + (id >> 3);
    const int x0 = (id2 % 12) << 4;
    const int y0 = ((id2 / 12) % 24) << 3;
    const int zz = id2 / 288;
    const int b  = zz & 3, which = zz >> 2;

    const float* in = which ? fm2 : fm1;
    const unsigned short* wfrag = which ? wfQ : wfK;
    const float* bias = which ? bQ : bK;
    const float* bn_g = which ? gQ : gK;
    const float* bn_be = which ? beQ : beK;
    const float* bn_m = which ? mQ : mK;
    const float* bn_v = which ? vQ : vK;
    unsigned short* out = which ? f2o : f1o;
    const float* inb = in + (size_t)b * 64 * 36864;

    if (x0 == 0) {
        for (int i = t; i < 640; i += 256) {
            int ci = i & 63, row = i >> 6;
            win[(row * 18 + 0) * NPAD + ci] = 0;
        }
    } else if (x0 == 176) {
        for (int i = t; i < 640; i += 256) {
            int ci = i & 63, row = i >> 6;
            win[(row * 18 + 17) * NPAD + ci] = 0;
        }
    }

    const int gxs = (x0 == 0) ? 0 : ((x0 == 176) ? 168 : x0 - 4);
    const int wv = t >> 6, l = t & 63;
    const int nt = wv & 1, mhalf = wv >> 1;
    const int c31 = l & 31, khl = l >> 5;
    const int cout = nt * 32 + c31;
    const unsigned short* wf = wfrag + (size_t)nt * 36 * 512 + l * 8;

    const float inv = bn_g[cout] / sqrtf(bn_v[cout] + EPSf);
    const float sh  = (bias[cout] - bn_m[cout]) * inv + bn_be[cout];

    f32x16 acc0, acc1;
#pragma unroll
    for (int i = 0; i < 16; ++i) { acc0[i] = 0.f; acc1[i] = 0.f; }

    const int px0 = (mhalf * 2 + 0) * 32 + c31;
    const int px1 = (mhalf * 2 + 1) * 32 + c31;
    const int py0 = px0 >> 4, pxx0 = px0 & 15;
    const int py1 = px1 >> 4, pxx1 = px1 & 15;

    // ---- stage half 0: ci[0,32) as 4 ci-octs x 10 rows x 6 j = 240 items ----
    if (t < 240) {
        int p = t / 6, j = t - p * 6;             // p: 0..39
        int co8 = p & 3, row = p >> 2;            // ci-oct, row 0..9
        int ci = co8 * 8;
        int gy = y0 - 1 + row;
        bool rowok = (gy >= 0 && gy < 192);
        int gya = rowok ? gy : (gy < 0 ? 0 : 191);
        int gxa = gxs + j * 4;
        const float* rp = inb + (size_t)ci * 36864 + gya * 192 + gxa;
        f32x4 v[8];
#pragma unroll
        for (int k = 0; k < 8; ++k) v[k] = *(const f32x4*)(rp + (size_t)k * 36864);
#pragma unroll
        for (int e = 0; e < 4; ++e) {
            int col = gxa + e - (x0 - 1);
            if (col >= 0 && col < 18) {
                short8 pk;
#pragma unroll
                for (int k = 0; k < 8; ++k)
                    ((unsigned short*)&pk)[k] = f32_to_bf16(rowok ? v[k][e] : 0.f);
                *(short8*)&win[(row * 18 + col) * NPAD + ci] = pk;
            }
        }
    }
    __syncthreads();

    // ---- issue half-1 staging (flies under phase-0 MFMAs via wave overlap) ----
    if (t < 240) {
        int p = t / 6, j = t - p * 6;
        int co8 = p & 3, row = p >> 2;
        int ci = 32 + co8 * 8;
        int gy = y0 - 1 + row;
        bool rowok = (gy >= 0 && gy < 192);
        int gya = rowok ? gy : (gy < 0 ? 0 : 191);
        int gxa = gxs + j * 4;
        const float* rp = inb + (size_t)ci * 36864 + gya * 192 + gxa;
        f32x4 v[8];
#pragma unroll
        for (int k = 0; k < 8; ++k) v[k] = *(const f32x4*)(rp + (size_t)k * 36864);
#pragma unroll
        for (int e = 0; e < 4; ++e) {
            int col = gxa + e - (x0 - 1);
            if (col >= 0 && col < 18) {
                short8 pk;
#pragma unroll
                for (int k = 0; k < 8; ++k)
                    ((unsigned short*)&pk)[k] = f32_to_bf16(rowok ? v[k][e] : 0.f);
                *(short8*)&win[(row * 18 + col) * NPAD + ci] = pk;
            }
        }
    }

    // ---- MFMA phase 0: cig in {0,1} (ci<32) ----
#pragma unroll
    for (int tap = 0; tap < 9; ++tap) {
#pragma unroll
        for (int cig = 0; cig < 2; ++cig) {
            int s = tap * 4 + cig;
            short8 bfr = *(const short8*)&wf[s * 512];
            int ky = tap / 3, kx = tap - ky * 3;
            int cb = cig * 16 + khl * 8;
            short8 a0 = *(const short8*)&win[((py0 + ky) * 18 + pxx0 + kx) * NPAD + cb];
            short8 a1 = *(const short8*)&win[((py1 + ky) * 18 + pxx1 + kx) * NPAD + cb];
            acc0 = __builtin_amdgcn_mfma_f32_32x32x16_bf16(a0, bfr, acc0, 0, 0, 0);
            acc1 = __builtin_amdgcn_mfma_f32_32x32x16_bf16(a1, bfr, acc1, 0, 0, 0);
        }
    }
    __syncthreads();

    // ---- MFMA phase 1: cig in {2,3} (ci>=32) ----
#pragma unroll
    for (int tap = 0; tap < 9; ++tap) {
#pragma unroll
        for (int cig = 2; cig < 4; ++cig) {
            int s = tap * 4 + cig;
            short8 bfr = *(const short8*)&wf[s * 512];
            int ky = tap / 3, kx = tap - ky * 3;
            int cb = cig * 16 + khl * 8;
            short8 a0 = *(const short8*)&win[((py0 + ky) * 18 + pxx0 + kx) * NPAD + cb];
            short8 a1 = *(const short8*)&win[((py1 + ky) * 18 + pxx1 + kx) * NPAD + cb];
            acc0 = __builtin_amdgcn_mfma_f32_32x32x16_bf16(a0, bfr, acc0, 0, 0, 0);
            acc1 = __builtin_amdgcn_mfma_f32_32x32x16_bf16(a1, bfr, acc1, 0, 0, 0);
        }
    }

    // ---- epilogue: D col = l&31 -> cout; row = (r&3)+8*(r>>2)+4*khl -> px ----
    const size_t pbase = (size_t)b * 36864;
#pragma unroll
    for (int mt2 = 0; mt2 < 2; ++mt2) {
#pragma unroll
        for (int r = 0; r < 16; ++r) {
            int rowm = (r & 3) + 8 * (r >> 2) + 4 * khl;
            int px = (mhalf * 2 + mt2) * 32 + rowm;
            int py = px >> 4, pxx = px & 15;
            float v = fmaf(mt2 ? acc1[r] : acc0[r], inv, sh);
            out[(pbase + (size_t)(y0 + py) * 192 + x0 + pxx) * 64 + cout] =
                f32_to_bf16(v > 0.f ? v : 0.f);
        }
    }
}

// Fused corr(R=4) + 1x1 conv — EXACT r28 version (validated, incl. XCD swizzle).
__global__ __launch_bounds__(256) void corr_conv1x1_mfma(
    const unsigned short* __restrict__ f1, const unsigned short* __restrict__ f2,
    const float* __restrict__ qw,
    const unsigned short* __restrict__ w2f,   // may be null
    const float* __restrict__ qb,
    const float* __restrict__ qg, const float* __restrict__ qbe,
    const float* __restrict__ qm, const float* __restrict__ qv,
    float* __restrict__ out)
{
    __shared__ unsigned short smem[20736 + 64 * CSTR];
    unsigned short* f2w  = smem;
    unsigned short* cbuf = smem + 20736;

    const int t  = threadIdx.x;
    const int id  = blockIdx.x + 12 * (blockIdx.y + 48 * blockIdx.z);
    const int id2 = (id & 7) * 288 + (id >> 3);
    const int x0 = (id2 % 12) << 4;
    const int y0 = ((id2 / 12) % 48) << 2;
    const int b  = id2 / 576;

    const int wv = t >> 6, l = t & 63;
    const int n15 = l & 15, kg = l >> 4, hi4 = kg << 2;
    const size_t pbase = (size_t)b * 36864;

#pragma unroll
    for (int i = 0; i < 9; ++i) {
        int q = t + (i << 8);
        int r = q / 192, rem = q - r * 192;
        int u = rem >> 3, j = rem & 7;
        int gy = y0 - 4 + r, gx = x0 - 4 + u;
        short8 v = {0, 0, 0, 0, 0, 0, 0, 0};
        if (gy >= 0 && gy < 192 && gx >= 0 && gx < 192)
            v = *(const short8*)&f2[(pbase + (size_t)gy * 192 + gx) * 64 + j * 8];
        *(short8*)&f2w[(r * 24 + u) * NPAD + j * 8] = v;
    }
#pragma unroll
    for (int i = 0; i < 2; ++i) {
        int q = t + (i << 8);
        int px = q >> 3, j = q & 7;
        int gy = y0 + (px >> 4), gx = x0 + (px & 15);
        short8 v = *(const short8*)&f1[(pbase + (size_t)gy * 192 + gx) * 64 + j * 8];
        *(short8*)&cbuf[px * CSTR + 88 + j * 8] = v;
    }
    if (t < 64) {
#pragma unroll
        for (int d = 81; d < 88; ++d)  cbuf[t * CSTR + d] = 0;
#pragma unroll
        for (int d = 152; d < 168; ++d) cbuf[t * CSTR + d] = 0;
    }

    short8 w2[5];
    if (w2f) {
#pragma unroll
        for (int s = 0; s < 5; ++s)
            w2[s] = *(const short8*)&w2f[((wv * 5 + s) * 64 + l) * 8];
    } else {
        const int cout_a = wv * 16 + n15;
#pragma unroll
        for (int s = 0; s < 5; ++s) {
            short8 v;
#pragma unroll
            for (int e = 0; e < 8; ++e) {
                int k = s * 32 + kg * 8 + e;
                float w = 0.f;
                if (k < 81)                  w = qw[cout_a * 145 + k];
                else if (k >= 88 && k < 152) w = qw[cout_a * 145 + k - 7];
                ((unsigned short*)&v)[e] = f32_to_bf16(w);
            }
            w2[s] = v;
        }
    }
    float inv4[4], sh4[4];
#pragma unroll
    for (int r = 0; r < 4; ++r) {
        int c = wv * 16 + hi4 + r;
        inv4[r] = qg[c] / sqrtf(qv[c] + EPSf);
        sh4[r]  = (qb[c] - qm[c]) * inv4[r] + qbe[c];
    }

    __syncthreads();

    const int ty = wv, tx = n15;
    short8 bfr0 = *(const short8*)&cbuf[(ty * 16 + n15) * CSTR + 88 + kg * 8];
    short8 bfr1 = *(const short8*)&cbuf[(ty * 16 + n15) * CSTR + 120 + kg * 8];
    const int rowb = (ty * 16 + tx) * CSTR;
#pragma unroll
    for (int Mt = 0; Mt < 14; ++Mt) {
        int row = ty * 24 + Mt * 16 + n15;
        short8 a0 = *(const short8*)&f2w[row * NPAD + kg * 8];
        short8 a1 = *(const short8*)&f2w[row * NPAD + 32 + kg * 8];
        f32x4 acc = (f32x4){0.f, 0.f, 0.f, 0.f};
        acc = __builtin_amdgcn_mfma_f32_16x16x32_bf16(a0, bfr0, acc, 0, 0, 0);
        acc = __builtin_amdgcn_mfma_f32_16x16x32_bf16(a1, bfr1, acc, 0, 0, 0);
#pragma unroll
        for (int r = 0; r < 4; ++r) {
            int m  = Mt * 16 + hi4 + r;
            int bb = m / 24;
            int u  = m - bb * 24;
            int a  = u - tx;
            if (m < 216 && a >= 0 && a <= 8)
                cbuf[rowb + a * 9 + bb] = f32_to_bf16(acc[r] * 0.125f);
        }
    }
    __syncthreads();

    f32x4 acc2[4];
#pragma unroll
    for (int Nt = 0; Nt < 4; ++Nt) {
        acc2[Nt] = (f32x4){0.f, 0.f, 0.f, 0.f};
#pragma unroll
        for (int s = 0; s < 5; ++s) {
            short8 bfr = *(const short8*)&cbuf[(Nt * 16 + n15) * CSTR + s * 32 + kg * 8];
            acc2[Nt] = __builtin_amdgcn_mfma_f32_16x16x32_bf16(w2[s], bfr, acc2[Nt], 0, 0, 0);
        }
    }
#pragma unroll
    for (int Nt = 0; Nt < 4; ++Nt) {
        int gy = y0 + Nt, gx = x0 + n15;
#pragma unroll
        for (int r = 0; r < 4; ++r) {
            int c = wv * 16 + hi4 + r;
            float v = fmaf(acc2[Nt][r], inv4[r], sh4[r]);
            out[((size_t)(b * 64 + c)) * 36864 + (size_t)gy * 192 + gx] = v > 0.f ? v : 0.f;
        }
    }
}

extern "C" void kernel_launch(void* const* d_in, const int* in_sizes, int n_in,
                              void* d_out, int out_size, void* d_ws, size_t ws_size,
                              hipStream_t stream) {
    float* out = (float*)d_out;

    unsigned short* f1 = (unsigned short*)d_ws;
    unsigned short* f2 = f1 + (size_t)4 * 64 * 36864;

    unsigned short* wfK = (unsigned short*)d_out + 18800640;
    unsigned short* wfQ = wfK + 36864;

    unsigned short* w2f = nullptr;
    if (ws_size >= 37748736ull + 20480ull)
        w2f = (unsigned short*)((char*)d_ws + 37748736);

    prep_all<<<dim3(3), 256, 0, stream>>>(
        (const float*)d_in[2], (const float*)d_in[8], (const float*)d_in[14],
        wfK, wfQ, w2f);

    dim3 cgrid(12, 24, 8);
    conv3x3_mfma_P<<<cgrid, 256, 0, stream>>>(
        (const float*)d_in[0], (const float*)d_in[1], wfK, wfQ,
        (const float*)d_in[3], (const float*)d_in[4], (const float*)d_in[5],
        (const float*)d_in[6], (const float*)d_in[7],
        (const float*)d_in[9], (const float*)d_in[10], (const float*)d_in[11],
        (const float*)d_in[12], (const float*)d_in[13],
        f1, f2);

    dim3 ggrid(12, 48, 4);
    corr_conv1x1_mfma<<<ggrid, 256, 0, stream>>>(
        f1, f2,
        (const float*)d_in[14], w2f,
        (const float*)d_in[15], (const float*)d_in[16],
        (const float*)d_in[17], (const float*)d_in[18], (const float*)d_in[19],
        out);
}